// Round 4
// baseline (216.502 us; speedup 1.0000x reference)
//
#include <hip/hip_runtime.h>
#include <hip/hip_bf16.h>
#include <hip/hip_cooperative_groups.h>

namespace cg = cooperative_groups;

// LinearCombiner: MLP has NO activation -> affine: out = M@x + c,
// M = W3@W2@W1 (8x3072), c = (W3@W2)@b1 + W3@b2 + b3, and
// x[t,u] = [min;max;user] separable -> out[t,u,o] = P[t,o]+Q[u,o]+c[o].
//
// ONE cooperative kernel (round-3 showed ~25us of inter-launch gaps):
//  ph1: part1 = W3@W2 partials (32 k-slices x 12 col-groups) + cp2 fold
//  ph2: self-reduce A-slice of M2 from part1 (98KB L2) ; part2 = M2@W1 + cp1
//  ph3: M = reduce(part2) [96 blks] ; c = sum(cp1+cp2)+b3 [1 blk]
//  ph4: P[t] (256 blks), Q[u] (128 blks)
//  ph5: out[t,u,:] = P[t]+Q[u]+c (128 blks)

#define HIDN 3072
#define DIM 1024
#define NOUT 8
#define NS 32            // k-slices
#define KPS 96           // rows per slice
#define WK 24            // rows per wave
#define GX 12            // column groups of 256 cols
#define TDIM 256
#define UDIM 128
#define NBLK 384         // GX*NS

__device__ __forceinline__ float dot4(float4 a, float4 b) {
    return a.x * b.x + a.y * b.y + a.z * b.z + a.w * b.w;
}

// part[s][o][h] += A-slice (in LDS) @ B rows of this slice; 4 waves split rows.
__device__ __forceinline__ void gemm_body(const float* __restrict__ B,
                                          float* __restrict__ part,
                                          const float* As, float4* red,
                                          int s, int gx, int lane, int w) {
    const int h = gx * 256 + lane * 4;
    const int k0 = s * KPS + w * WK;
    float4 acc[NOUT];
#pragma unroll
    for (int o = 0; o < NOUT; ++o) acc[o] = make_float4(0.f, 0.f, 0.f, 0.f);
    const float4* Bp = (const float4*)(B + (size_t)k0 * HIDN) + (h >> 2);
#pragma unroll 8
    for (int kk = 0; kk < WK; ++kk) {
        float4 bv = Bp[(size_t)kk * (HIDN / 4)];
#pragma unroll
        for (int o = 0; o < NOUT; ++o) {
            float a = As[o * KPS + w * WK + kk];
            acc[o].x += a * bv.x; acc[o].y += a * bv.y;
            acc[o].z += a * bv.z; acc[o].w += a * bv.w;
        }
    }
#pragma unroll
    for (int o = 0; o < NOUT; ++o) red[(w * NOUT + o) * 64 + lane] = acc[o];
    __syncthreads();
#pragma unroll
    for (int j = 0; j < 2; ++j) {
        const int o = w * 2 + j;
        float4 v0 = red[(0 * NOUT + o) * 64 + lane];
        float4 v1 = red[(1 * NOUT + o) * 64 + lane];
        float4 v2 = red[(2 * NOUT + o) * 64 + lane];
        float4 v3 = red[(3 * NOUT + o) * 64 + lane];
        *(float4*)(part + ((size_t)s * NOUT + o) * HIDN + h) =
            make_float4(v0.x + v1.x + v2.x + v3.x, v0.y + v1.y + v2.y + v3.y,
                        v0.z + v1.z + v2.z + v3.z, v0.w + v1.w + v2.w + v3.w);
    }
}

// fold cpX[s][o] = sum_kk As[o][kk] * bvec[s*KPS+kk]  (32 lanes per o)
__device__ __forceinline__ void bias_slice_fold(const float* As,
                                                const float* __restrict__ bvec,
                                                float* __restrict__ cp,
                                                int s, int tid) {
    const int o = tid >> 5, k5 = tid & 31;
    float acc = 0.f;
#pragma unroll
    for (int j = 0; j < KPS / 32; ++j)
        acc += As[o * KPS + k5 + 32 * j] * bvec[s * KPS + k5 + 32 * j];
#pragma unroll
    for (int off = 16; off; off >>= 1) acc += __shfl_down(acc, off, 32);
    if (k5 == 0) cp[s * NOUT + o] = acc;
}

__global__ __launch_bounds__(256) void fused_all(
    const float* __restrict__ text_a, const float* __restrict__ text_b,
    const float* __restrict__ user,
    const float* __restrict__ W1, const float* __restrict__ b1,
    const float* __restrict__ W2, const float* __restrict__ b2,
    const float* __restrict__ W3, const float* __restrict__ b3,
    float* __restrict__ part1, float* __restrict__ part2,
    float* __restrict__ M, float* __restrict__ c,
    float* __restrict__ cp1, float* __restrict__ cp2,
    float* __restrict__ P, float* __restrict__ Q,
    float4* __restrict__ out)
{
    cg::grid_group grid = cg::this_grid();
    const int b = blockIdx.x;
    const int tid = threadIdx.x;
    const int lane = tid & 63, w = tid >> 6;

    __shared__ float As[NOUT * KPS];          // 3 KB
    __shared__ float4 red[4 * NOUT * 64];     // 32 KB

    const int s = b / GX, gx = b % GX;

    // ---------- phase 1: part1 = W3 @ W2 ; cp2 ----------
    for (int i = tid; i < NOUT * KPS; i += 256)
        As[i] = W3[(i / KPS) * HIDN + s * KPS + (i % KPS)];
    __syncthreads();
    if (gx == 0) bias_slice_fold(As, b2, cp2, s, tid);
    gemm_body(W2, part1, As, red, s, gx, lane, w);

    grid.sync();

    // ---------- phase 2: As = M2 slice (self-reduce) ; part2 = M2 @ W1 ; cp1
    for (int j = tid; j < NOUT * KPS; j += 256) {
        const int o = j / KPS, kk = j % KPS;
        const float* pp = part1 + (size_t)o * HIDN + s * KPS + kk;
        float a = 0.f;
#pragma unroll 8
        for (int sp = 0; sp < NS; ++sp) a += pp[(size_t)sp * (NOUT * HIDN)];
        As[j] = a;
    }
    __syncthreads();
    if (gx == 0) bias_slice_fold(As, b1, cp1, s, tid);
    gemm_body(W1, part2, As, red, s, gx, lane, w);

    grid.sync();

    // ---------- phase 3: M = reduce(part2) [b<96] ; c [b==96] ----------
    if (b < 96) {
        const int i4 = b * 64 + lane;          // [0, NOUT*HIDN/4)
        const float4* p2 = (const float4*)part2;
        float4 acc = make_float4(0.f, 0.f, 0.f, 0.f);
#pragma unroll
        for (int j = 0; j < NS / 4; ++j) {
            float4 v = p2[(size_t)(w * (NS / 4) + j) * (NOUT * HIDN / 4) + i4];
            acc.x += v.x; acc.y += v.y; acc.z += v.z; acc.w += v.w;
        }
        red[w * 64 + lane] = acc;
        __syncthreads();
        if (w == 0) {
            float4 a0 = red[lane], a1 = red[64 + lane];
            float4 a2 = red[128 + lane], a3 = red[192 + lane];
            ((float4*)M)[i4] = make_float4(
                a0.x + a1.x + a2.x + a3.x, a0.y + a1.y + a2.y + a3.y,
                a0.z + a1.z + a2.z + a3.z, a0.w + a1.w + a2.w + a3.w);
        }
    } else if (b == 96 && tid < NOUT) {
        float acc = b3[tid];
        for (int s2 = 0; s2 < NS; ++s2)
            acc += cp1[s2 * NOUT + tid] + cp2[s2 * NOUT + tid];
        c[tid] = acc;
    }

    grid.sync();

    // ---------- phase 4: proj P (b<256), Q (256<=b<384) ----------
    {
        const int d = tid * 4;
        float acc[NOUT];
        if (b < TDIM) {
            const int t = b;
            float4 a = *(const float4*)(text_a + t * DIM + d);
            float4 bb = *(const float4*)(text_b + t * DIM + d);
            float4 mn = make_float4(fminf(a.x, bb.x), fminf(a.y, bb.y),
                                    fminf(a.z, bb.z), fminf(a.w, bb.w));
            float4 mx = make_float4(fmaxf(a.x, bb.x), fmaxf(a.y, bb.y),
                                    fmaxf(a.z, bb.z), fmaxf(a.w, bb.w));
#pragma unroll
            for (int o = 0; o < NOUT; ++o) {
                float4 ml = *(const float4*)(M + o * HIDN + d);
                float4 mh = *(const float4*)(M + o * HIDN + DIM + d);
                acc[o] = dot4(ml, mn) + dot4(mh, mx);
            }
        } else {
            const int u = b - TDIM;
            float4 x = *(const float4*)(user + u * DIM + d);
#pragma unroll
            for (int o = 0; o < NOUT; ++o) {
                float4 m = *(const float4*)(M + o * HIDN + 2 * DIM + d);
                acc[o] = dot4(m, x);
            }
        }
#pragma unroll
        for (int o = 0; o < NOUT; ++o) {
#pragma unroll
            for (int off = 32; off > 0; off >>= 1)
                acc[o] += __shfl_down(acc[o], off, 64);
        }
        float* rf = (float*)red;               // [4][NOUT]
        if (lane == 0) {
#pragma unroll
            for (int o = 0; o < NOUT; ++o) rf[w * NOUT + o] = acc[o];
        }
        __syncthreads();
        float* dst = (b < TDIM) ? (P + b * NOUT) : (Q + (b - TDIM) * NOUT);
        if (tid < NOUT)
            dst[tid] = rf[tid] + rf[NOUT + tid] + rf[2 * NOUT + tid] + rf[3 * NOUT + tid];
    }

    grid.sync();

    // ---------- phase 5: combine (b<128) ----------
    if (b < 128) {
        const int idx = b * 256 + tid;         // [0, T*U)
        const int t = idx >> 7, u = idx & (UDIM - 1);
        const float4* Pp = (const float4*)(P) + t * 2;
        const float4* Qp = (const float4*)(Q) + u * 2;
        const float4* Cp = (const float4*)(c);
        float4 p0 = Pp[0], p1 = Pp[1];
        float4 q0 = Qp[0], q1 = Qp[1];
        float4 c0 = Cp[0], c1 = Cp[1];
        out[idx * 2]     = make_float4(p0.x + q0.x + c0.x, p0.y + q0.y + c0.y,
                                       p0.z + q0.z + c0.z, p0.w + q0.w + c0.w);
        out[idx * 2 + 1] = make_float4(p1.x + q1.x + c1.x, p1.y + q1.y + c1.y,
                                       p1.z + q1.z + c1.z, p1.w + q1.w + c1.w);
    }
}

extern "C" void kernel_launch(void* const* d_in, const int* in_sizes, int n_in,
                              void* d_out, int out_size, void* d_ws, size_t ws_size,
                              hipStream_t stream) {
    const float* text_a = (const float*)d_in[0];
    const float* text_b = (const float*)d_in[1];
    const float* user   = (const float*)d_in[2];
    const float* W1 = (const float*)d_in[3];
    const float* b1 = (const float*)d_in[4];
    const float* W2 = (const float*)d_in[5];
    const float* b2 = (const float*)d_in[6];
    const float* W3 = (const float*)d_in[7];
    const float* b3 = (const float*)d_in[8];

    float* ws = (float*)d_ws;
    float* part1 = ws;                                  // 786432 floats
    float* part2 = part1 + (size_t)NS * NOUT * HIDN;    // 786432
    float* M  = part2 + (size_t)NS * NOUT * HIDN;       // 24576
    float* c  = M + NOUT * HIDN;                        // 8
    float* cp1 = c + NOUT;                              // 256
    float* cp2 = cp1 + NS * NOUT;                       // 256
    float* P  = cp2 + NS * NOUT;                        // 2048 (16B aligned)
    float* Q  = P + TDIM * NOUT;                        // 1024
    float4* outp = (float4*)d_out;

    void* args[] = {
        (void*)&text_a, (void*)&text_b, (void*)&user,
        (void*)&W1, (void*)&b1, (void*)&W2, (void*)&b2, (void*)&W3, (void*)&b3,
        (void*)&part1, (void*)&part2, (void*)&M, (void*)&c,
        (void*)&cp1, (void*)&cp2, (void*)&P, (void*)&Q, (void*)&outp
    };
    hipLaunchCooperativeKernel((const void*)fused_all, dim3(NBLK), dim3(256),
                               args, 0, stream);
}

// Round 5
// 34.013 us; speedup vs baseline: 6.3653x; 6.3653x over previous
//
#include <hip/hip_runtime.h>
#include <hip/hip_bf16.h>

// LinearCombiner: MLP has NO activation -> affine: out = M@x + c,
// M = W3@W2@W1 (8x3072), c = (W3@W2)@b1 + W3@b2 + b3, and
// x[t,u] = [min;max;user] separable -> out[t,u,o] = P[t,o]+Q[u,o]+c[o].
//
// Round-4 lesson: cooperative grid.sync() costs ~50us/sync on gfx950 (8
// non-coherent XCD L2s) -> back to multi-launch. 5 launches, 4 gaps:
//  K1 gemm (mode 0): part1 = W3@W2 partials (+ cp2[s] = W3_slice . b2)
//  K2 gemm (mode 1): As = self-reduced M2 slice from part1 (L2-hot),
//                    part2 = M2@W1 partials (+ cp1[s] = M2_slice . b1)
//  K3: M = reduce(part2) [96 blks] ; c = sum(cp1+cp2)+b3 [1 blk]
//  K4: proj P (256 blks), Q (128 blks)
//  K5: combine out[t,u,:] = P[t]+Q[u]+c
//
// GEMM inner loop: all 24 float4 B-loads hoisted (full unroll, static idx ->
// VGPRs) so ~24KB/wave stays in flight -> HBM-BW-bound, not latency-bound.

#define HIDN 3072
#define DIM 1024
#define NOUT 8
#define NS 32            // k-slices
#define KPS 96           // rows per slice
#define WK 24            // rows per wave (KPS/4)
#define GX 12            // column groups of 256 cols
#define TDIM 256
#define UDIM 128

__device__ __forceinline__ float dot4(float4 a, float4 b) {
    return a.x * b.x + a.y * b.y + a.z * b.z + a.w * b.w;
}

// fold cp[s][o] = sum_kk As[o][kk] * bvec[s*KPS+kk]  (32 lanes per o)
__device__ __forceinline__ void bias_slice_fold(const float* As,
                                                const float* __restrict__ bvec,
                                                float* __restrict__ cp,
                                                int s, int tid) {
    const int o = tid >> 5, k5 = tid & 31;
    float acc = 0.f;
#pragma unroll
    for (int j = 0; j < KPS / 32; ++j)
        acc += As[o * KPS + k5 + 32 * j] * bvec[s * KPS + k5 + 32 * j];
#pragma unroll
    for (int off = 16; off; off >>= 1) acc += __shfl_down(acc, off, 32);
    if (k5 == 0) cp[s * NOUT + o] = acc;
}

// mode 0: A_rows (8,HIDN) read directly. mode 1: A slice self-reduced from
// part_in (sum over 32 slice-partials, L2/L3-hot).
// part_out[s][o][h] = sum_{k in slice s} A[o,k] * B[k,h]
__global__ __launch_bounds__(256) void gemm_partial(
    const float* __restrict__ A_rows, const float* __restrict__ part_in,
    const float* __restrict__ B, float* __restrict__ part_out,
    const float* __restrict__ bvec, float* __restrict__ cp, int mode) {
    const int s = blockIdx.y, gx = blockIdx.x;
    const int tid = threadIdx.x;
    const int lane = tid & 63, w = tid >> 6;

    __shared__ float As[NOUT * KPS];          // 3 KB
    __shared__ float4 red[4 * NOUT * 64];     // 32 KB

    if (mode == 0) {
        for (int i = tid; i < NOUT * KPS; i += 256)
            As[i] = A_rows[(i / KPS) * HIDN + s * KPS + (i % KPS)];
    } else {
        // As[o][kk] = sum_sp part_in[sp][o][s*KPS+kk], float4 over kk
        for (int j4 = tid; j4 < NOUT * KPS / 4; j4 += 256) {
            const int o = j4 / (KPS / 4), kk4 = j4 % (KPS / 4);
            const float4* pp = (const float4*)(part_in + (size_t)o * HIDN
                                               + s * KPS) + kk4;
            float4 a = make_float4(0.f, 0.f, 0.f, 0.f);
#pragma unroll 8
            for (int sp = 0; sp < NS; ++sp) {
                float4 v = pp[(size_t)sp * (NOUT * HIDN / 4)];
                a.x += v.x; a.y += v.y; a.z += v.z; a.w += v.w;
            }
            ((float4*)As)[j4] = a;
        }
    }
    __syncthreads();
    if (gx == 0) bias_slice_fold(As, bvec, cp, s, tid);

    const int h = gx * 256 + lane * 4;
    const int k0 = s * KPS + w * WK;
    const float4* Bp = (const float4*)(B + (size_t)k0 * HIDN) + (h >> 2);

    // hoist all 24 row-loads (static indices -> VGPRs, ~24KB in flight/wave)
    float4 bv[WK];
#pragma unroll
    for (int kk = 0; kk < WK; ++kk) bv[kk] = Bp[(size_t)kk * (HIDN / 4)];

    float4 acc[NOUT];
#pragma unroll
    for (int o = 0; o < NOUT; ++o) acc[o] = make_float4(0.f, 0.f, 0.f, 0.f);
#pragma unroll
    for (int kk = 0; kk < WK; ++kk) {
#pragma unroll
        for (int o = 0; o < NOUT; ++o) {
            float a = As[o * KPS + w * WK + kk];
            acc[o].x += a * bv[kk].x; acc[o].y += a * bv[kk].y;
            acc[o].z += a * bv[kk].z; acc[o].w += a * bv[kk].w;
        }
    }

    // cross-wave reduce: publish, wave w sums outputs {2w, 2w+1}
#pragma unroll
    for (int o = 0; o < NOUT; ++o) red[(w * NOUT + o) * 64 + lane] = acc[o];
    __syncthreads();
#pragma unroll
    for (int j = 0; j < 2; ++j) {
        const int o = w * 2 + j;
        float4 v0 = red[(0 * NOUT + o) * 64 + lane];
        float4 v1 = red[(1 * NOUT + o) * 64 + lane];
        float4 v2 = red[(2 * NOUT + o) * 64 + lane];
        float4 v3 = red[(3 * NOUT + o) * 64 + lane];
        *(float4*)(part_out + ((size_t)s * NOUT + o) * HIDN + h) =
            make_float4(v0.x + v1.x + v2.x + v3.x, v0.y + v1.y + v2.y + v3.y,
                        v0.z + v1.z + v2.z + v3.z, v0.w + v1.w + v2.w + v3.w);
    }
}

// blocks 0..95: M = reduce(part2). block 96: c = sum_s(cp1+cp2) + b3.
__global__ __launch_bounds__(256) void reduce_M_c(const float* __restrict__ part,
                                                  const float* __restrict__ cp1,
                                                  const float* __restrict__ cp2,
                                                  const float* __restrict__ b3,
                                                  float* __restrict__ M,
                                                  float* __restrict__ c) {
    const int b = blockIdx.x, tid = threadIdx.x;
    if (b == 96) {
        if (tid < NOUT) {
            float acc = b3[tid];
            for (int s = 0; s < NS; ++s)
                acc += cp1[s * NOUT + tid] + cp2[s * NOUT + tid];
            c[tid] = acc;
        }
        return;
    }
    const int lane = tid & 63, w = tid >> 6;
    const int i4 = b * 64 + lane;              // [0, NOUT*HIDN/4)
    const float4* p = (const float4*)part;
    float4 acc = make_float4(0.f, 0.f, 0.f, 0.f);
#pragma unroll
    for (int j = 0; j < NS / 4; ++j) {
        float4 v = p[(size_t)(w * (NS / 4) + j) * (NOUT * HIDN / 4) + i4];
        acc.x += v.x; acc.y += v.y; acc.z += v.z; acc.w += v.w;
    }
    __shared__ float4 red[4 * 64];
    red[w * 64 + lane] = acc;
    __syncthreads();
    if (w == 0) {
        float4 a0 = red[lane], a1 = red[64 + lane];
        float4 a2 = red[128 + lane], a3 = red[192 + lane];
        ((float4*)M)[i4] = make_float4(
            a0.x + a1.x + a2.x + a3.x, a0.y + a1.y + a2.y + a3.y,
            a0.z + a1.z + a2.z + a3.z, a0.w + a1.w + a2.w + a3.w);
    }
}

// blocks [0,256): P[t,o] ; blocks [256,384): Q[u,o]
__global__ __launch_bounds__(256) void proj(const float* __restrict__ ta,
                                            const float* __restrict__ tb,
                                            const float* __restrict__ user,
                                            const float* __restrict__ M,
                                            float* __restrict__ P,
                                            float* __restrict__ Q) {
    const int tid = threadIdx.x;
    const int bid = blockIdx.x;
    const int lane = tid & 63, w = tid >> 6;
    const int d = tid * 4;
    float acc[NOUT];

    if (bid < TDIM) {
        const int t = bid;
        float4 a = *(const float4*)(ta + t * DIM + d);
        float4 b = *(const float4*)(tb + t * DIM + d);
        float4 mn = make_float4(fminf(a.x, b.x), fminf(a.y, b.y),
                                fminf(a.z, b.z), fminf(a.w, b.w));
        float4 mx = make_float4(fmaxf(a.x, b.x), fmaxf(a.y, b.y),
                                fmaxf(a.z, b.z), fmaxf(a.w, b.w));
#pragma unroll
        for (int o = 0; o < NOUT; ++o) {
            float4 ml = *(const float4*)(M + o * HIDN + d);
            float4 mh = *(const float4*)(M + o * HIDN + DIM + d);
            acc[o] = dot4(ml, mn) + dot4(mh, mx);
        }
    } else {
        const int u = bid - TDIM;
        float4 x = *(const float4*)(user + u * DIM + d);
#pragma unroll
        for (int o = 0; o < NOUT; ++o) {
            float4 m = *(const float4*)(M + o * HIDN + 2 * DIM + d);
            acc[o] = dot4(m, x);
        }
    }

#pragma unroll
    for (int o = 0; o < NOUT; ++o) {
#pragma unroll
        for (int off = 32; off > 0; off >>= 1)
            acc[o] += __shfl_down(acc[o], off, 64);
    }
    __shared__ float red[4][NOUT];
    if (lane == 0) {
#pragma unroll
        for (int o = 0; o < NOUT; ++o) red[w][o] = acc[o];
    }
    __syncthreads();
    float* dst = (bid < TDIM) ? (P + bid * NOUT) : (Q + (bid - TDIM) * NOUT);
    if (tid < NOUT) dst[tid] = red[0][tid] + red[1][tid] + red[2][tid] + red[3][tid];
}

// out[t,u,o] = P[t,o] + Q[u,o] + c[o]
__global__ __launch_bounds__(256) void combine_out(const float* __restrict__ P,
                                                   const float* __restrict__ Q,
                                                   const float* __restrict__ c,
                                                   float4* __restrict__ out) {
    const int idx = blockIdx.x * 256 + threadIdx.x;  // [0, T*U)
    const int t = idx >> 7, u = idx & (UDIM - 1);
    const float4* Pp = (const float4*)(P) + t * 2;
    const float4* Qp = (const float4*)(Q) + u * 2;
    const float4* Cp = (const float4*)(c);
    float4 p0 = Pp[0], p1 = Pp[1];
    float4 q0 = Qp[0], q1 = Qp[1];
    float4 c0 = Cp[0], c1 = Cp[1];
    out[idx * 2]     = make_float4(p0.x + q0.x + c0.x, p0.y + q0.y + c0.y,
                                   p0.z + q0.z + c0.z, p0.w + q0.w + c0.w);
    out[idx * 2 + 1] = make_float4(p1.x + q1.x + c1.x, p1.y + q1.y + c1.y,
                                   p1.z + q1.z + c1.z, p1.w + q1.w + c1.w);
}

extern "C" void kernel_launch(void* const* d_in, const int* in_sizes, int n_in,
                              void* d_out, int out_size, void* d_ws, size_t ws_size,
                              hipStream_t stream) {
    const float* text_a = (const float*)d_in[0];
    const float* text_b = (const float*)d_in[1];
    const float* user   = (const float*)d_in[2];
    const float* W1 = (const float*)d_in[3];
    const float* b1 = (const float*)d_in[4];
    const float* W2 = (const float*)d_in[5];
    const float* b2 = (const float*)d_in[6];
    const float* W3 = (const float*)d_in[7];
    const float* b3 = (const float*)d_in[8];

    float* ws = (float*)d_ws;
    float* part1 = ws;                                  // 786432 floats
    float* part2 = part1 + (size_t)NS * NOUT * HIDN;    // 786432
    float* M  = part2 + (size_t)NS * NOUT * HIDN;       // 24576
    float* c  = M + NOUT * HIDN;                        // 8
    float* cp1 = c + NOUT;                              // 256
    float* cp2 = cp1 + NS * NOUT;                       // 256
    float* P  = cp2 + NS * NOUT;                        // 2048 (16B aligned)
    float* Q  = P + TDIM * NOUT;                        // 1024

    // K1: part1 = W3 @ W2 ; cp2
    gemm_partial<<<dim3(GX, NS), 256, 0, stream>>>(W3, nullptr, W2, part1,
                                                   b2, cp2, 0);
    // K2: As = M2 slice (self-reduce from part1) ; part2 = M2 @ W1 ; cp1
    gemm_partial<<<dim3(GX, NS), 256, 0, stream>>>(nullptr, part1, W1, part2,
                                                   b1, cp1, 1);
    // K3: M = reduce(part2) ; c
    reduce_M_c<<<97, 256, 0, stream>>>(part2, cp1, cp2, b3, M, c);
    // K4: P, Q
    proj<<<TDIM + UDIM, 256, 0, stream>>>(text_a, text_b, user, M, P, Q);
    // K5: out
    combine_out<<<(TDIM * UDIM) / 256, 256, 0, stream>>>(P, Q, c, (float4*)d_out);
}